// Round 5
// baseline (977.777 us; speedup 1.0000x reference)
//
#include <hip/hip_runtime.h>
#include <hip/hip_bf16.h>
#include <stdint.h>

#define CDIM 768
#define HDIM 48

typedef float  f32x4  __attribute__((ext_vector_type(4)));
typedef short  bf16x8 __attribute__((ext_vector_type(8)));
typedef unsigned short u16x4 __attribute__((ext_vector_type(4)));

__device__ __forceinline__ unsigned short f2bf(float x) {
    __hip_bfloat16 h = __float2bfloat16(x);   // HW RNE convert
    return *reinterpret_cast<unsigned short*>(&h);
}
#define SB0() __builtin_amdgcn_sched_barrier(0)

// ---------------- prep: pack weights into MFMA fragment order ----------------
// (unchanged — verified correct in R1/R2)
__global__ __launch_bounds__(256) void prep_kernel(
    const float* __restrict__ W1, const float* __restrict__ b1,
    const float* __restrict__ W2,
    const float* __restrict__ gamma, const float* __restrict__ beta,
    unsigned short* __restrict__ w1p, unsigned short* __restrict__ w2p,
    float* __restrict__ b1p, float* __restrict__ cs1)
{
    const int blk = blockIdx.x, tid = threadIdx.x;
    const int l = tid & 63;
    if (blk < 18) {                       // 72 W1 frags, 4/block
        const int fid = blk * 4 + (tid >> 6);
        const int kt = fid / 3, nt = fid % 3;
        const int k0 = kt * 32 + 8 * (l >> 4);
        const int n  = nt * 16 + (l & 15);
        bf16x8 v;
        #pragma unroll
        for (int b = 0; b < 8; ++b) {
            const int k = k0 + b;
            v[b] = (short)f2bf(gamma[k] * W1[k * HDIM + n]);
        }
        *reinterpret_cast<bf16x8*>(w1p + (size_t)(fid * 64 + l) * 8) = v;
    } else if (blk < 42) {                // 96 W2 frags, 4/block
        const int fid = (blk - 18) * 4 + (tid >> 6);
        const int kt = fid / 48, nt = fid % 48;
        const int k0 = kt * 32 + 8 * (l >> 4);
        const int n  = nt * 16 + (l & 15);
        bf16x8 v;
        #pragma unroll
        for (int b = 0; b < 8; ++b) {
            const int k = k0 + b;
            const float w = (k < HDIM) ? W2[k * CDIM + n] : 0.0f;
            v[b] = (short)f2bf(w);
        }
        *reinterpret_cast<bf16x8*>(w2p + (size_t)(fid * 64 + l) * 8) = v;
    } else {                              // b1p / cs1 reductions
        const int j = tid >> 2, p = tid & 3;
        float sb = 0.f, sg = 0.f;
        if (j < HDIM) {
            for (int c = p * 192; c < (p + 1) * 192; ++c) {
                const float w = W1[c * HDIM + j];
                sb += beta[c]  * w;
                sg += gamma[c] * w;
            }
        }
        sb += __shfl_xor(sb, 1); sb += __shfl_xor(sb, 2);
        sg += __shfl_xor(sg, 1); sg += __shfl_xor(sg, 2);
        if (p == 0 && j < HDIM) { b1p[j] = b1[j] + sb; cs1[j] = sg; }
    }
}

// ---------------- main fused kernel ----------------
// R5 core rule: ONE vmcnt FIFO => ALL streams prefetched at the SAME distance.
// GEMM1 per-iter: issue pair [w(kt+3), x(kt+3)] adjacently, then compute kt.
// Waiting for pair(kt) retires only pairs <= kt; pairs kt+1..kt+3 stay in
// flight (~3KB x + 2.25KB w per wave). Ring size 4 > distance 3: no
// self-overwrite. GEMM2 keeps the (already distance-matched) R4 structure.
__global__ __launch_bounds__(256, 2) void mlp_kernel(
    const float* __restrict__ x,
    const float* __restrict__ b2g,
    const unsigned short* __restrict__ w1p,
    const unsigned short* __restrict__ w2p,
    const float* __restrict__ b1p,
    const float* __restrict__ cs1,
    float* __restrict__ out,
    int tiles)
{
    __shared__ __align__(16) unsigned short lds_hid[4][16][72]; // stride 72 -> 2-way banks (free)
    __shared__ __align__(16) float lds_b2[CDIM];
    __shared__ __align__(16) float lds_b1[HDIM];
    __shared__ __align__(16) float lds_cs[HDIM];

    const int tid  = threadIdx.x;
    const int w    = tid >> 6;
    const int l    = tid & 63;
    const int lrow = l & 15;    // row within 16-row tile
    const int lg   = l >> 4;    // k-group

    // one-time stage of small constants into LDS (keeps them out of the vmcnt FIFO)
    if (tid < 192)       reinterpret_cast<f32x4*>(lds_b2)[tid]       = reinterpret_cast<const f32x4*>(b2g)[tid];
    else if (tid < 204)  reinterpret_cast<f32x4*>(lds_b1)[tid - 192] = reinterpret_cast<const f32x4*>(b1p)[tid - 192];
    else if (tid < 216)  reinterpret_cast<f32x4*>(lds_cs)[tid - 204] = reinterpret_cast<const f32x4*>(cs1)[tid - 204];
    __syncthreads();

    // zero the k-pad region (cols 48..63) of this wave's hid tile, once
    *reinterpret_cast<unsigned long long*>(&lds_hid[w][l >> 2][48 + (l & 3) * 4]) = 0ull;

    const bf16x8* __restrict__ w1f = reinterpret_cast<const bf16x8*>(w1p);
    const bf16x8* __restrict__ w2f = reinterpret_cast<const bf16x8*>(w2p);

    const int waveId    = blockIdx.x * 4 + w;
    const int waveCount = gridDim.x * 4;

    #pragma unroll 1
    for (int t = waveId; t < tiles; t += waveCount) {
        const size_t m0 = (size_t)t * 16;
        const float* __restrict__ xrow = x + (m0 + lrow) * CDIM + 8 * lg;

        // ================= GEMM1: hid_raw = x @ W1'  (+ row stats) =================
        f32x4  xq[4][2];
        bf16x8 wq[4][3];
        f32x4  acc1[3];
        #pragma unroll
        for (int nt = 0; nt < 3; ++nt) {
            acc1[nt][0] = 0.f; acc1[nt][1] = 0.f; acc1[nt][2] = 0.f; acc1[nt][3] = 0.f;
        }
        // prologue: pairs 0..2, each [w first, x second] to fix FIFO age classes
        #pragma unroll
        for (int i = 0; i < 3; ++i) {
            #pragma unroll
            for (int nt = 0; nt < 3; ++nt)
                wq[i][nt] = w1f[(i * 3 + nt) * 64 + l];
            xq[i][0] = *reinterpret_cast<const f32x4*>(xrow + i * 32);
            xq[i][1] = *reinterpret_cast<const f32x4*>(xrow + i * 32 + 4);
        }
        SB0();

        float rsum = 0.f, rsq = 0.f;
        #pragma unroll
        for (int kt = 0; kt < 24; ++kt) {
            // SSA capture of pair kt (safety; slot kt&3 != (kt+3)&3 anyway)
            const bf16x8 wa = wq[kt & 3][0];
            const bf16x8 wb = wq[kt & 3][1];
            const bf16x8 wc = wq[kt & 3][2];
            const f32x4  xa = xq[kt & 3][0];
            const f32x4  xb = xq[kt & 3][1];
            // distance-matched prefetch of pair kt+3: w first, x second, adjacent
            if (kt + 3 < 24) {
                const int s = (kt + 3) & 3;
                #pragma unroll
                for (int nt = 0; nt < 3; ++nt)
                    wq[s][nt] = w1f[((kt + 3) * 3 + nt) * 64 + l];
                xq[s][0] = *reinterpret_cast<const f32x4*>(xrow + (kt + 3) * 32);
                xq[s][1] = *reinterpret_cast<const f32x4*>(xrow + (kt + 3) * 32 + 4);
            }
            SB0();   // loads above, compute below
            bf16x8 bf;
            #pragma unroll
            for (int b = 0; b < 4; ++b) {
                rsum += xa[b]; rsq += xa[b] * xa[b];
                rsum += xb[b]; rsq += xb[b] * xb[b];
                bf[b]     = (short)f2bf(xa[b]);
                bf[b + 4] = (short)f2bf(xb[b]);
            }
            acc1[0] = __builtin_amdgcn_mfma_f32_16x16x32_bf16(wa, bf, acc1[0], 0, 0, 0);
            acc1[1] = __builtin_amdgcn_mfma_f32_16x16x32_bf16(wb, bf, acc1[1], 0, 0, 0);
            acc1[2] = __builtin_amdgcn_mfma_f32_16x16x32_bf16(wc, bf, acc1[2], 0, 0, 0);
            SB0();   // keep next iter's loads from sinking below this compute
        }
        rsum += __shfl_xor(rsum, 16); rsum += __shfl_xor(rsum, 32);
        rsq  += __shfl_xor(rsq , 16); rsq  += __shfl_xor(rsq , 32);
        const float mu   = rsum * (1.f / 768.f);
        const float var  = rsq * (1.f / 768.f) - mu * mu;
        const float rstd = rsqrtf(var + 1e-5f);

        // ---- LN fixup + bias + QuickGELU -> LDS bf16 (constants from LDS) ----
        #pragma unroll
        for (int nt = 0; nt < 3; ++nt) {
            const int c4 = nt * 16 + 4 * lg;
            const f32x4 bb = *reinterpret_cast<const f32x4*>(&lds_b1[c4]);
            const f32x4 cs = *reinterpret_cast<const f32x4*>(&lds_cs[c4]);
            u16x4 pk;
            #pragma unroll
            for (int r = 0; r < 4; ++r) {
                const float h = rstd * (acc1[nt][r] - mu * cs[r]) + bb[r];
                const float g = h / (1.f + __expf(-1.702f * h));
                pk[r] = f2bf(g);
            }
            *reinterpret_cast<u16x4*>(&lds_hid[w][lrow][c4]) = pk;
        }
        // wave-synchronous LDS handoff (same wave writes+reads; lgkmcnt-ordered)
        const bf16x8 a2_0 = *reinterpret_cast<const bf16x8*>(&lds_hid[w][lrow][8 * lg]);
        const bf16x8 a2_1 = *reinterpret_cast<const bf16x8*>(&lds_hid[w][lrow][8 * lg + 32]);

        const float* __restrict__ xres = x   + (m0 + lrow) * CDIM;
        float* __restrict__       ores = out + (m0 + lrow) * CDIM;

        // ===== GEMM2: 24 chunks x 2 ctiles, distance-2 matched pairs (verified) =====
        bf16x8 w2q[3][2][2];
        f32x4  resq[3][2];
        #pragma unroll
        for (int j = 0; j < 2; ++j) {                        // prologue: pairs 0,1
            #pragma unroll
            for (int c = 0; c < 2; ++c) {
                const int ct = j * 2 + c;
                w2q[j][c][0] = w2f[ct * 64 + l];
                w2q[j][c][1] = w2f[(48 + ct) * 64 + l];
            }
            #pragma unroll
            for (int c = 0; c < 2; ++c)
                resq[j][c] = *reinterpret_cast<const f32x4*>(xres + (j * 2 + c) * 16 + 4 * lg);
        }
        SB0();
        #pragma unroll
        for (int j = 0; j < 24; ++j) {
            if (j + 2 < 24) {
                const int js = (j + 2) % 3;
                #pragma unroll
                for (int c = 0; c < 2; ++c) {                // w2 first
                    const int ct = (j + 2) * 2 + c;
                    w2q[js][c][0] = w2f[ct * 64 + l];
                    w2q[js][c][1] = w2f[(48 + ct) * 64 + l];
                }
                #pragma unroll
                for (int c = 0; c < 2; ++c)                  // then residual, same distance
                    resq[js][c] = *reinterpret_cast<const f32x4*>(xres + ((j + 2) * 2 + c) * 16 + 4 * lg);
            }
            SB0();   // loads above, compute below
            #pragma unroll
            for (int c = 0; c < 2; ++c) {
                const int ct = j * 2 + c;
                f32x4 acc2 = {0.f, 0.f, 0.f, 0.f};
                acc2 = __builtin_amdgcn_mfma_f32_16x16x32_bf16(w2q[j % 3][c][0], a2_0, acc2, 0, 0, 0);
                acc2 = __builtin_amdgcn_mfma_f32_16x16x32_bf16(w2q[j % 3][c][1], a2_1, acc2, 0, 0, 0);
                const int c4 = ct * 16 + 4 * lg;
                const f32x4 bb = *reinterpret_cast<const f32x4*>(&lds_b2[c4]);
                f32x4 o;
                #pragma unroll
                for (int r = 0; r < 4; ++r) o[r] = acc2[r] + bb[r] + resq[j % 3][c][r];
                *reinterpret_cast<f32x4*>(ores + c4) = o;
            }
            SB0();
        }
    }
}

extern "C" void kernel_launch(void* const* d_in, const int* in_sizes, int n_in,
                              void* d_out, int out_size, void* d_ws, size_t ws_size,
                              hipStream_t stream)
{
    const float* x     = (const float*)d_in[0];
    const float* W1    = (const float*)d_in[1];
    const float* b1    = (const float*)d_in[2];
    const float* W2    = (const float*)d_in[3];
    const float* b2    = (const float*)d_in[4];
    const float* gamma = (const float*)d_in[5];
    const float* beta  = (const float*)d_in[6];
    float* out = (float*)d_out;

    unsigned short* w1p = (unsigned short*)d_ws;     // 72 frags * 512 B  = 73728 B
    unsigned short* w2p = w1p + 24 * 3 * 64 * 8;     // 96 frags * 512 B  = 98304 B
    float* b1p = (float*)(w2p + 2 * 48 * 64 * 8);    // 48 f32
    float* cs1 = b1p + 64;                           // 48 f32 (16B-aligned gap)

    const int M = in_sizes[0] / CDIM;   // 131072 rows
    const int tiles = M / 16;           // 8192

    prep_kernel<<<dim3(43), dim3(256), 0, stream>>>(W1, b1, W2, gamma, beta, w1p, w2p, b1p, cs1);
    mlp_kernel<<<dim3(tiles / 4), dim3(256), 0, stream>>>(x, b2, w1p, w2p, b1p, cs1, out, tiles);
}

// Round 6
// 265.497 us; speedup vs baseline: 3.6828x; 3.6828x over previous
//
#include <hip/hip_runtime.h>
#include <hip/hip_bf16.h>
#include <stdint.h>

#define CDIM 768
#define HDIM 48
#define NCH  8        // K chunks per group (96 floats each)

typedef float  f32x4  __attribute__((ext_vector_type(4)));
typedef short  bf16x8 __attribute__((ext_vector_type(8)));
typedef unsigned short u16x4 __attribute__((ext_vector_type(4)));

__device__ __forceinline__ unsigned short f2bf(float x) {
    __hip_bfloat16 h = __float2bfloat16(x);   // HW RNE convert
    return *reinterpret_cast<unsigned short*>(&h);
}
#define SB0() __builtin_amdgcn_sched_barrier(0)
#define BAR() __builtin_amdgcn_s_barrier()
#define CFENCE() asm volatile("" ::: "memory")

__device__ __forceinline__ void gload_lds16(const void* g, void* l) {
    __builtin_amdgcn_global_load_lds(
        (const __attribute__((address_space(1))) unsigned int*)g,
        (__attribute__((address_space(3))) unsigned int*)l, 16, 0, 0);
}

// ---------------- prep: pack weights into MFMA fragment order ----------------
// (unchanged — verified correct since R1)
__global__ __launch_bounds__(256) void prep_kernel(
    const float* __restrict__ W1, const float* __restrict__ b1,
    const float* __restrict__ W2,
    const float* __restrict__ gamma, const float* __restrict__ beta,
    unsigned short* __restrict__ w1p, unsigned short* __restrict__ w2p,
    float* __restrict__ b1p, float* __restrict__ cs1)
{
    const int blk = blockIdx.x, tid = threadIdx.x;
    const int l = tid & 63;
    if (blk < 18) {                       // 72 W1 frags, 4/block
        const int fid = blk * 4 + (tid >> 6);
        const int kt = fid / 3, nt = fid % 3;
        const int k0 = kt * 32 + 8 * (l >> 4);
        const int n  = nt * 16 + (l & 15);
        bf16x8 v;
        #pragma unroll
        for (int b = 0; b < 8; ++b) {
            const int k = k0 + b;
            v[b] = (short)f2bf(gamma[k] * W1[k * HDIM + n]);
        }
        *reinterpret_cast<bf16x8*>(w1p + (size_t)(fid * 64 + l) * 8) = v;
    } else if (blk < 42) {                // 96 W2 frags, 4/block
        const int fid = (blk - 18) * 4 + (tid >> 6);
        const int kt = fid / 48, nt = fid % 48;
        const int k0 = kt * 32 + 8 * (l >> 4);
        const int n  = nt * 16 + (l & 15);
        bf16x8 v;
        #pragma unroll
        for (int b = 0; b < 8; ++b) {
            const int k = k0 + b;
            const float w = (k < HDIM) ? W2[k * CDIM + n] : 0.0f;
            v[b] = (short)f2bf(w);
        }
        *reinterpret_cast<bf16x8*>(w2p + (size_t)(fid * 64 + l) * 8) = v;
    } else {                              // b1p / cs1 reductions
        const int j = tid >> 2, p = tid & 3;
        float sb = 0.f, sg = 0.f;
        if (j < HDIM) {
            for (int c = p * 192; c < (p + 1) * 192; ++c) {
                const float w = W1[c * HDIM + j];
                sb += beta[c]  * w;
                sg += gamma[c] * w;
            }
        }
        sb += __shfl_xor(sb, 1); sb += __shfl_xor(sb, 2);
        sg += __shfl_xor(sg, 1); sg += __shfl_xor(sg, 2);
        if (p == 0 && j < HDIM) { b1p[j] = b1[j] + sb; cs1[j] = sg; }
    }
}

// ---------------- main fused kernel ----------------
// GEMM1 x-feed via async global_load_lds double-buffer, counted vmcnt(6)
// (never 0 mid-loop), raw s_barrier (no implicit drain). LDS rows XOR-swizzled
// (byte ^= (row&7)<<4) on BOTH sides: pre-swizzled global src (gload_lds dest
// must stay linear) + swizzled ds_read. FIFO invariant entering chunk cc:
// [x(cc):6, w(cc):9, x(cc+1):6] -> vmcnt(6) retires x(cc),w(cc) exactly.
__global__ __launch_bounds__(256, 2) void mlp_kernel(
    const float* __restrict__ x,
    const float* __restrict__ b2g,
    const unsigned short* __restrict__ w1p,
    const unsigned short* __restrict__ w2p,
    const float* __restrict__ b1p,
    const float* __restrict__ cs1,
    float* __restrict__ out)
{
    __shared__ __align__(16) float lds_x[2][6144];              // 2 x 24 KB (64 rows x 96 cols)
    __shared__ __align__(16) unsigned short lds_hid[4][16][72]; // stride 72 -> 2-way banks (free)
    __shared__ __align__(16) float lds_b2[CDIM];
    __shared__ __align__(16) float lds_b1[HDIM];
    __shared__ __align__(16) float lds_cs[HDIM];

    const int tid  = threadIdx.x;
    const int w    = tid >> 6;
    const int l    = tid & 63;
    const int lrow = l & 15;
    const int lg   = l >> 4;

    // one-time: consts -> LDS; zero hid k-pad (cols 48..63)
    if (tid < 192)       reinterpret_cast<f32x4*>(lds_b2)[tid]       = reinterpret_cast<const f32x4*>(b2g)[tid];
    else if (tid < 204)  reinterpret_cast<f32x4*>(lds_b1)[tid - 192] = reinterpret_cast<const f32x4*>(b1p)[tid - 192];
    else if (tid < 216)  reinterpret_cast<f32x4*>(lds_cs)[tid - 204] = reinterpret_cast<const f32x4*>(cs1)[tid - 204];
    *reinterpret_cast<unsigned long long*>(&lds_hid[w][l >> 2][48 + (l & 3) * 4]) = 0ull;
    __syncthreads();   // full drain: clean vmcnt baseline before the pipeline

    // per-thread staging source offsets (pre-swizzled): this thread's 6 x 16B
    // granules land linearly at LDS bytes (w*6+j)*1024 + l*16; the global
    // element placed there is (row, col_logical = col_phys ^ ((row&7)<<4)).
    int srcoff[6];
    #pragma unroll
    for (int j = 0; j < 6; ++j) {
        const int o   = (w * 6 + j) * 1024 + l * 16;   // byte offset in 24KB chunk image
        const int row = o / 384;                       // 0..63  (384 B per row-chunk)
        const int cph = o % 384;
        const int clg = cph ^ ((row & 7) << 4);        // logical col bytes
        srcoff[j] = row * 3072 + clg;                  // 3072 B per full row of x
    }

    const size_t grow0 = (size_t)blockIdx.x * 64;      // group's first row
    const char* const xg = (const char*)x + grow0 * 3072;

    const bf16x8* __restrict__ w1f = reinterpret_cast<const bf16x8*>(w1p);
    const bf16x8* __restrict__ w2f = reinterpret_cast<const bf16x8*>(w2p);

    // ---- prologue: x(0)->buf0, w(0)->wq[0], x(1)->buf1  (FIFO: 6,9,6)
    #pragma unroll
    for (int j = 0; j < 6; ++j)
        gload_lds16(xg + 0 * 384 + srcoff[j], (char*)&lds_x[0][0] + (w * 6 + j) * 1024);
    bf16x8 wq[2][9];
    #pragma unroll
    for (int q = 0; q < 9; ++q) wq[0][q] = w1f[q * 64 + l];
    #pragma unroll
    for (int j = 0; j < 6; ++j)
        gload_lds16(xg + 1 * 384 + srcoff[j], (char*)&lds_x[1][0] + (w * 6 + j) * 1024);

    const int myrow   = (w << 4) | lrow;               // this lane's row in group
    const int rowbase = myrow * 384;
    const int rxor    = (myrow & 7) << 4;

    f32x4 acc1[3];
    #pragma unroll
    for (int nt = 0; nt < 3; ++nt) { acc1[nt][0]=0.f; acc1[nt][1]=0.f; acc1[nt][2]=0.f; acc1[nt][3]=0.f; }
    float rsum = 0.f, rsq = 0.f;

    #pragma unroll
    for (int cc = 0; cc < NCH; ++cc) {
        // A: retire x(cc)+w(cc); keep x(cc+1) in flight (counted, not drained)
        if (cc < NCH - 1) asm volatile("s_waitcnt vmcnt(6)" ::: "memory");
        else              asm volatile("s_waitcnt vmcnt(0)" ::: "memory");
        BAR();             // B: buf[cc&1] fully landed for ALL waves
        CFENCE();
        // C: pull this wave's chunk rows into regs (swizzled ds_read)
        const char* bufb = (const char*)&lds_x[cc & 1][0];
        f32x4 xr[6];
        #pragma unroll
        for (int ktl = 0; ktl < 3; ++ktl) {
            xr[ktl*2+0] = *reinterpret_cast<const f32x4*>(bufb + rowbase + ((ktl*128 + lg*32 +  0) ^ rxor));
            xr[ktl*2+1] = *reinterpret_cast<const f32x4*>(bufb + rowbase + ((ktl*128 + lg*32 + 16) ^ rxor));
        }
        asm volatile("s_waitcnt lgkmcnt(0)" ::: "memory");
        SB0();
        BAR();             // D: all waves drained buf[cc&1] -> safe to overwrite
        CFENCE();
        // E: issue w(cc+1)  (9 loads, L2-resident)
        if (cc + 1 < NCH) {
            #pragma unroll
            for (int q = 0; q < 9; ++q)
                wq[(cc + 1) & 1][q] = w1f[((cc + 1) * 9 + q) * 64 + l];
        }
        // F: issue x(cc+2) -> buf[cc&1] (async DMA, no VGPR cost)
        if (cc + 2 < NCH) {
            #pragma unroll
            for (int j = 0; j < 6; ++j)
                gload_lds16(xg + (cc + 2) * 384 + srcoff[j], (char*)&lds_x[cc & 1][0] + (w * 6 + j) * 1024);
        }
        // G: compute chunk cc (3 ktiles) + row stats
        #pragma unroll
        for (int ktl = 0; ktl < 3; ++ktl) {
            const f32x4 xa = xr[ktl*2+0];
            const f32x4 xb = xr[ktl*2+1];
            bf16x8 bf;
            #pragma unroll
            for (int b = 0; b < 4; ++b) {
                rsum += xa[b]; rsq += xa[b] * xa[b];
                rsum += xb[b]; rsq += xb[b] * xb[b];
                bf[b]     = (short)f2bf(xa[b]);
                bf[b + 4] = (short)f2bf(xb[b]);
            }
            acc1[0] = __builtin_amdgcn_mfma_f32_16x16x32_bf16(wq[cc & 1][ktl*3+0], bf, acc1[0], 0, 0, 0);
            acc1[1] = __builtin_amdgcn_mfma_f32_16x16x32_bf16(wq[cc & 1][ktl*3+1], bf, acc1[1], 0, 0, 0);
            acc1[2] = __builtin_amdgcn_mfma_f32_16x16x32_bf16(wq[cc & 1][ktl*3+2], bf, acc1[2], 0, 0, 0);
        }
    }

    rsum += __shfl_xor(rsum, 16); rsum += __shfl_xor(rsum, 32);
    rsq  += __shfl_xor(rsq , 16); rsq  += __shfl_xor(rsq , 32);
    const float mu   = rsum * (1.f / 768.f);
    const float var  = rsq * (1.f / 768.f) - mu * mu;
    const float rstd = rsqrtf(var + 1e-5f);

    // ---- LN fixup + bias + QuickGELU -> LDS bf16 ----
    #pragma unroll
    for (int nt = 0; nt < 3; ++nt) {
        const int c4 = nt * 16 + 4 * lg;
        const f32x4 bb = *reinterpret_cast<const f32x4*>(&lds_b1[c4]);
        const f32x4 cs = *reinterpret_cast<const f32x4*>(&lds_cs[c4]);
        u16x4 pk;
        #pragma unroll
        for (int r = 0; r < 4; ++r) {
            const float h = rstd * (acc1[nt][r] - mu * cs[r]) + bb[r];
            const float g = h / (1.f + __expf(-1.702f * h));
            pk[r] = f2bf(g);
        }
        *reinterpret_cast<u16x4*>(&lds_hid[w][lrow][c4]) = pk;
    }
    // wave-synchronous LDS handoff (same wave writes+reads; lgkmcnt-ordered)
    const bf16x8 a2_0 = *reinterpret_cast<const bf16x8*>(&lds_hid[w][lrow][8 * lg]);
    const bf16x8 a2_1 = *reinterpret_cast<const bf16x8*>(&lds_hid[w][lrow][8 * lg + 32]);

    const size_t m0 = grow0 + (size_t)w * 16;
    const float* __restrict__ xres = x   + (m0 + lrow) * CDIM;
    float* __restrict__       ores = out + (m0 + lrow) * CDIM;

    // ===== GEMM2 (R2-verbatim): 6 chunks x 8 ctiles, residual issued first =====
    #pragma unroll 1
    for (int ch = 0; ch < 6; ++ch) {
        f32x4 res[8];
        #pragma unroll
        for (int n8 = 0; n8 < 8; ++n8)
            res[n8] = *reinterpret_cast<const f32x4*>(xres + (ch * 8 + n8) * 16 + 4 * lg);
        f32x4 acc2[8];
        #pragma unroll
        for (int n8 = 0; n8 < 8; ++n8) { acc2[n8][0]=0.f; acc2[n8][1]=0.f; acc2[n8][2]=0.f; acc2[n8][3]=0.f; }
        #pragma unroll
        for (int n8 = 0; n8 < 8; ++n8) {
            const int ct = ch * 8 + n8;
            acc2[n8] = __builtin_amdgcn_mfma_f32_16x16x32_bf16(w2f[ct * 64 + l],        a2_0, acc2[n8], 0, 0, 0);
            acc2[n8] = __builtin_amdgcn_mfma_f32_16x16x32_bf16(w2f[(48 + ct) * 64 + l], a2_1, acc2[n8], 0, 0, 0);
        }
        #pragma unroll
        for (int n8 = 0; n8 < 8; ++n8) {
            const int c4 = (ch * 8 + n8) * 16 + 4 * lg;
            const f32x4 bb = *reinterpret_cast<const f32x4*>(&lds_b2[c4]);
            f32x4 o;
            #pragma unroll
            for (int r = 0; r < 4; ++r) o[r] = acc2[n8][r] + bb[r] + res[n8][r];
            *reinterpret_cast<f32x4*>(ores + c4) = o;
        }
    }
}

extern "C" void kernel_launch(void* const* d_in, const int* in_sizes, int n_in,
                              void* d_out, int out_size, void* d_ws, size_t ws_size,
                              hipStream_t stream)
{
    const float* x     = (const float*)d_in[0];
    const float* W1    = (const float*)d_in[1];
    const float* b1    = (const float*)d_in[2];
    const float* W2    = (const float*)d_in[3];
    const float* b2    = (const float*)d_in[4];
    const float* gamma = (const float*)d_in[5];
    const float* beta  = (const float*)d_in[6];
    float* out = (float*)d_out;

    unsigned short* w1p = (unsigned short*)d_ws;     // 72 frags * 512 B  = 73728 B
    unsigned short* w2p = w1p + 24 * 3 * 64 * 8;     // 96 frags * 512 B  = 98304 B
    float* b1p = (float*)(w2p + 2 * 48 * 64 * 8);    // 48 f32
    float* cs1 = b1p + 64;                           // 48 f32 (16B-aligned gap)

    const int M = in_sizes[0] / CDIM;   // 131072 rows
    const int groups = M / 64;          // 2048 blocks, one 64-row group each

    prep_kernel<<<dim3(43), dim3(256), 0, stream>>>(W1, b1, W2, gamma, beta, w1p, w2p, b1p, cs1);
    mlp_kernel<<<dim3(groups), dim3(256), 0, stream>>>(x, b2, w1p, w2p, b1p, cs1, out);
}